// Round 8
// baseline (334.307 us; speedup 1.0000x reference)
//
#include <hip/hip_runtime.h>

typedef unsigned short ushort_t;
typedef __attribute__((ext_vector_type(8))) short short8;
typedef __attribute__((ext_vector_type(4))) float f32x4;
typedef __attribute__((ext_vector_type(2))) unsigned uint2v;
typedef __attribute__((ext_vector_type(4))) unsigned uint4v;

#define DIM 1024
#define BATCH 8
#define NSEQ 1024
#define HEADS 16
#define HD 64

__device__ __forceinline__ ushort_t f2b(float f) {
    union { float f; unsigned u; } v; v.f = f;
    unsigned r = v.u + 0x7FFF + ((v.u >> 16) & 1);
    return (ushort_t)(r >> 16);
}

__device__ __forceinline__ unsigned cvtpk_bf16(float a, float b) {
    unsigned r;
    asm("v_cvt_pk_bf16_f32 %0, %1, %2" : "=v"(r) : "v"(a), "v"(b));
    return r;
}

__device__ __forceinline__ void g2l16(const void* g, void* l) {
    __builtin_amdgcn_global_load_lds(
        (const __attribute__((address_space(1))) void*)g,
        (__attribute__((address_space(3))) void*)l, 16, 0, 0);
}

// ------- fp32 -> bf16 convert, all 5 tensors in one launch; zeroes sync counters ----
__global__ __launch_bounds__(256) void conv_all(const float4* __restrict__ x,
                                                const float4* __restrict__ y,
                                                const float4* __restrict__ wq,
                                                const float4* __restrict__ wk,
                                                const float4* __restrict__ wv,
                                                short8* __restrict__ xb,
                                                short8* __restrict__ yb,
                                                short8* __restrict__ wqb,
                                                short8* __restrict__ wkb,
                                                short8* __restrict__ wvb,
                                                int* __restrict__ counters) {
    int j = blockIdx.x;
    if (j == 0 && threadIdx.x < 64) counters[threadIdx.x] = 0;
    const float4* src; short8* dst; int base;
    if (j < 4096)      { src = x;  dst = xb;  base = j; }
    else if (j < 8192) { src = y;  dst = yb;  base = j - 4096; }
    else if (j < 8704) { src = wq; dst = wqb; base = j - 8192; }
    else if (j < 9216) { src = wk; dst = wkb; base = j - 8704; }
    else               { src = wv; dst = wvb; base = j - 9216; }
    int i = base * 256 + threadIdx.x;
    float4 a = src[i * 2], b = src[i * 2 + 1];
    short8 o;
    o[0] = (short)f2b(a.x); o[1] = (short)f2b(a.y);
    o[2] = (short)f2b(a.z); o[3] = (short)f2b(a.w);
    o[4] = (short)f2b(b.x); o[5] = (short)f2b(b.y);
    o[6] = (short)f2b(b.z); o[7] = (short)f2b(b.w);
    dst[i] = o;
}

// ---------------- NT GEMM: C[M,N] = scale * A[M,K] * B[N,K]^T ----------------
// MODE decodes a 1D 512-block grid so panel-sharing blocks land on one XCD (bid%8).
// EXPOUT (MODE 3 only): fused column-softmax — write exp2(acc*scale)/colsum in one
// pass using intra-XCD group sync (8 blocks per (bz,bx) group, all on XCD bz).
template <typename OutT, int MODE, bool EXPOUT>
__global__ __launch_bounds__(256) void gemm_nt(const ushort_t* __restrict__ A,
                                               const ushort_t* __restrict__ B,
                                               OutT* __restrict__ C,
                                               long sA, long sB, long sC,
                                               float scale,
                                               float* __restrict__ partial,
                                               int* __restrict__ counters) {
    __shared__ __align__(16) ushort_t As[128 * 64];
    __shared__ __align__(16) ushort_t Bs[128 * 64];
    const int tid = threadIdx.x;
    const int w = tid >> 6, l = tid & 63;
    const int wm = w >> 1, wn = w & 1;
    const int lo = l & 15, hi = l >> 4;

    int bx, by, bz;
    const int j = blockIdx.x;
    if constexpr (MODE == 1) { by = j & 63; bx = j >> 6; bz = 0; }
    else if constexpr (MODE == 2) { bx = j & 7; by = (j >> 3) & 7; bz = j >> 6; }
    else { bz = j & 7; bx = (j >> 3) & 7; by = j >> 6; }

    const long abase = (long)by * 128 * 1024 + (long)bz * sA;
    const long bbase = (long)bx * 128 * 1024 + (long)bz * sB;
    const char* Abytes = (const char*)A;
    const char* Bbytes = (const char*)B;

    f32x4 acc[4][4];
#pragma unroll
    for (int m = 0; m < 4; m++)
#pragma unroll
        for (int n = 0; n < 4; n++) acc[m][n] = (f32x4)0.f;

    for (int kt = 0; kt < 1024; kt += 64) {
#pragma unroll
        for (int i = 0; i < 4; i++) {
            int o16 = tid + i * 256;
            int row = o16 >> 3;
            int cb = (o16 & 7) * 16;
            int scb = cb ^ ((row & 7) << 4);
            g2l16(Abytes + (abase + (long)row * 1024 + kt) * 2 + scb,
                  (char*)As + o16 * 16);
            g2l16(Bbytes + (bbase + (long)row * 1024 + kt) * 2 + scb,
                  (char*)Bs + o16 * 16);
        }
        __syncthreads();
#pragma unroll
        for (int kc = 0; kc < 2; kc++) {
            short8 af[4], bfr[4];
#pragma unroll
            for (int m = 0; m < 4; m++) {
                int row = wm * 64 + m * 16 + lo;
                int cb = (kc * 64 + hi * 16) ^ ((row & 7) << 4);
                af[m] = *(const short8*)((const char*)As + row * 128 + cb);
            }
#pragma unroll
            for (int n = 0; n < 4; n++) {
                int row = wn * 64 + n * 16 + lo;
                int cb = (kc * 64 + hi * 16) ^ ((row & 7) << 4);
                bfr[n] = *(const short8*)((const char*)Bs + row * 128 + cb);
            }
            __builtin_amdgcn_s_setprio(1);
#pragma unroll
            for (int m = 0; m < 4; m++)
#pragma unroll
                for (int n = 0; n < 4; n++)
                    acc[m][n] = __builtin_amdgcn_mfma_f32_16x16x32_bf16(
                        af[m], bfr[n], acc[m][n], 0, 0, 0);
            __builtin_amdgcn_s_setprio(0);
        }
        __syncthreads();
    }

    const long cb0 = (long)bz * sC;
    if constexpr (EXPOUT) {
        // exponentiate in-register; per-column partial sums (k = by*2+wm slice)
#pragma unroll
        for (int n = 0; n < 4; n++) {
            float csum = 0.f;
#pragma unroll
            for (int m = 0; m < 4; m++)
#pragma unroll
                for (int r = 0; r < 4; r++) {
                    float e = exp2f(acc[m][n][r] * scale);
                    acc[m][n][r] = e;
                    csum += e;
                }
            csum += __shfl_xor(csum, 16);
            csum += __shfl_xor(csum, 32);
            if (hi == 0)
                partial[((long)bz << 14) + (by * 2 + wm) * 1024 +
                        bx * 128 + wn * 64 + n * 16 + lo] = csum;
        }
        __threadfence();
        __syncthreads();
        const int g = bz * 8 + bx;
        if (tid == 0) {
            atomicAdd(&counters[g], 1);
            while (atomicAdd(&counters[g], 0) < 8) __builtin_amdgcn_s_sleep(2);
        }
        __syncthreads();
        __threadfence();
        // reduce the 16 partial slices for this block's 128 columns in LDS
        float* red = (float*)As;  // 16*128 + 128 floats = 8.5 KB
#pragma unroll
        for (int i = 0; i < 8; i++) {
            int idx = tid * 8 + i;  // 0..2047
            int k = idx >> 7, c = idx & 127;
            red[idx] = partial[((long)bz << 14) + k * 1024 + bx * 128 + c];
        }
        __syncthreads();
        if (tid < 128) {
            float s = 0.f;
#pragma unroll
            for (int k = 0; k < 16; k++) s += red[k * 128 + tid];
            red[2048 + tid] = 1.f / s;
        }
        __syncthreads();
        float iv[4];
#pragma unroll
        for (int n = 0; n < 4; n++) iv[n] = red[2048 + wn * 64 + n * 16 + lo];
#pragma unroll
        for (int m = 0; m < 4; m++)
#pragma unroll
            for (int n = 0; n < 4; n++)
#pragma unroll
                for (int r = 0; r < 4; r++) {
                    long row = (long)by * 128 + wm * 64 + m * 16 + hi * 4 + r;
                    long col = (long)bx * 128 + wn * 64 + n * 16 + lo;
                    C[cb0 + row * 1024 + col] = (OutT)(acc[m][n][r] * iv[n]);
                }
    } else {
#pragma unroll
        for (int m = 0; m < 4; m++)
#pragma unroll
            for (int n = 0; n < 4; n++)
#pragma unroll
                for (int r = 0; r < 4; r++) {
                    long row = (long)by * 128 + wm * 64 + m * 16 + hi * 4 + r;
                    long col = (long)bx * 128 + wn * 64 + n * 16 + lo;
                    float v = acc[m][n][r] * scale;
                    if constexpr (sizeof(OutT) == 2)
                        C[cb0 + row * 1024 + col] = (OutT)f2b(v);
                    else
                        C[cb0 + row * 1024 + col] = v;
                }
    }
}

// ---------------- fused flash attention ----------------
// 4 waves x 32 q = 128 q/block. KV tile 64, double-buffered LDS (32 KB).
// Swapped QK^T; raw exp2 (no max tracking); P in registers via cvt_pk+permlane;
// softmax denominator via ones-MFMA (row sums land in o_acc's C-layout).
__global__ __launch_bounds__(256, 4) void flash_attn(const ushort_t* __restrict__ Q,
                                                     const ushort_t* __restrict__ Kb,
                                                     const ushort_t* __restrict__ Vt,
                                                     ushort_t* __restrict__ Yo) {
    __shared__ __align__(16) ushort_t Ks[2][64 * 64];   // [key][d], swizzled
    __shared__ __align__(16) ushort_t Vs[2][64 * 64];   // [d][k],  swizzled
    const int j = blockIdx.x;
    const int g = j & 127, qt = j >> 7;
    const int h = g & 15, b = g >> 4;
    const int tid = threadIdx.x, w = tid >> 6, l = tid & 63;
    const int lo = l & 15, hi = l >> 4;
    const int sw = (lo & 7) << 4;  // K/V row swizzle (128B rows)

    const char* Khb = (const char*)(Kb + (long)b * 1024 * 1024 + h * 64);
    const char* Vhb = (const char*)(Vt + (long)b * 1024 * 1024 + (long)h * 64 * 1024);

    const long qrow0 = (long)b * 1024 + qt * 128 + w * 32;
    short8 qf[2][2];
#pragma unroll
    for (int qg = 0; qg < 2; qg++)
#pragma unroll
        for (int dk = 0; dk < 2; dk++)
            qf[qg][dk] = *(const short8*)(Q + (qrow0 + qg * 16 + lo) * 1024 +
                                          h * 64 + dk * 32 + hi * 8);

    short8 ones;
#pragma unroll
    for (int i = 0; i < 8; i++) ones[i] = (short)0x3F80;  // bf16 1.0

    f32x4 o_acc[4][2], o_sum[2];
#pragma unroll
    for (int ch = 0; ch < 4; ch++)
#pragma unroll
        for (int qg = 0; qg < 2; qg++) o_acc[ch][qg] = (f32x4)0.f;
    o_sum[0] = (f32x4)0.f; o_sum[1] = (f32x4)0.f;

    {
#pragma unroll
        for (int i = 0; i < 2; i++) {
            int o16 = tid + i * 256;
            int row = o16 >> 3, cb = (o16 & 7) * 16;
            int scb = cb ^ ((row & 7) << 4);
            g2l16(Khb + (long)row * 2048 + scb, (char*)Ks[0] + o16 * 16);
            g2l16(Vhb + (long)row * 2048 + scb, (char*)Vs[0] + o16 * 16);
        }
    }

    for (int t = 0; t < 16; t++) {
        __syncthreads();
        if (t < 15) {
            int kt = (t + 1) * 64;
            int bufn = (t + 1) & 1;
#pragma unroll
            for (int i = 0; i < 2; i++) {
                int o16 = tid + i * 256;
                int row = o16 >> 3, cb = (o16 & 7) * 16;
                int scb = cb ^ ((row & 7) << 4);
                g2l16(Khb + ((long)(kt + row) * 1024) * 2 + scb,
                      (char*)Ks[bufn] + o16 * 16);
                g2l16(Vhb + ((long)row * 1024 + kt) * 2 + scb,
                      (char*)Vs[bufn] + o16 * 16);
            }
        }
        const char* Kc = (const char*)Ks[t & 1];
        const char* Vc = (const char*)Vs[t & 1];

        // QK^T swapped: s_acc[ks][qg][r] = S[key=ks*16+hi*4+r][q=qg*16+lo] (log2 units)
        f32x4 s_acc[4][2];
        __builtin_amdgcn_s_setprio(1);
#pragma unroll
        for (int ks = 0; ks < 4; ks++) {
            const char* kr = Kc + (ks * 16 + lo) * 128;
            short8 kf0 = *(const short8*)(kr + ((hi * 16) ^ sw));
            short8 kf1 = *(const short8*)(kr + ((64 + hi * 16) ^ sw));
#pragma unroll
            for (int qg = 0; qg < 2; qg++) {
                s_acc[ks][qg] = __builtin_amdgcn_mfma_f32_16x16x32_bf16(
                    kf0, qf[qg][0], (f32x4)0.f, 0, 0, 0);
                s_acc[ks][qg] = __builtin_amdgcn_mfma_f32_16x16x32_bf16(
                    kf1, qf[qg][1], s_acc[ks][qg], 0, 0, 0);
            }
        }
        __builtin_amdgcn_s_setprio(0);

        // p = exp2(s) raw; pack to bf16 words (denominator comes from ones-MFMA)
        unsigned pk[2][4][2];  // [qg][ks][r2]
#pragma unroll
        for (int qg = 0; qg < 2; qg++)
#pragma unroll
            for (int ks = 0; ks < 4; ks++) {
#pragma unroll
                for (int r = 0; r < 4; r++)
                    s_acc[ks][qg][r] = exp2f(s_acc[ks][qg][r]);
                pk[qg][ks][0] = cvtpk_bf16(s_acc[ks][qg][0], s_acc[ks][qg][1]);
                pk[qg][ks][1] = cvtpk_bf16(s_acc[ks][qg][2], s_acc[ks][qg][3]);
            }

        // PV: redistribute P across hi-groups in-register, then MFMA (+ row sums).
#pragma unroll
        for (int kk = 0; kk < 2; kk++) {
            short8 pa[2];
#pragma unroll
            for (int qg = 0; qg < 2; qg++) {
                unsigned a0 = pk[qg][2 * kk][0], b0 = pk[qg][2 * kk + 1][0];
                uint2v t0 = __builtin_amdgcn_permlane32_swap(a0, b0, false, false);
                t0 = __builtin_amdgcn_permlane16_swap(t0[0], t0[1], false, false);
                unsigned a1 = pk[qg][2 * kk][1], b1 = pk[qg][2 * kk + 1][1];
                uint2v t1 = __builtin_amdgcn_permlane32_swap(a1, b1, false, false);
                t1 = __builtin_amdgcn_permlane16_swap(t1[0], t1[1], false, false);
                union { uint4v u; short8 s; } cv;
                cv.u = (uint4v){t0[0], t1[0], t0[1], t1[1]};
                pa[qg] = cv.s;
            }
            __builtin_amdgcn_s_setprio(1);
#pragma unroll
            for (int qg = 0; qg < 2; qg++)
                o_sum[qg] = __builtin_amdgcn_mfma_f32_16x16x32_bf16(
                    pa[qg], ones, o_sum[qg], 0, 0, 0);
#pragma unroll
            for (int ch = 0; ch < 4; ch++) {
                short8 vf = *(const short8*)(Vc + (ch * 16 + lo) * 128 +
                                             ((kk * 64 + hi * 16) ^ sw));
#pragma unroll
                for (int qg = 0; qg < 2; qg++)
                    o_acc[ch][qg] = __builtin_amdgcn_mfma_f32_16x16x32_bf16(
                        pa[qg], vf, o_acc[ch][qg], 0, 0, 0);
            }
            __builtin_amdgcn_s_setprio(0);
        }
    }

    // epilogue: o_sum already in C-layout per (qg, hi*4+r); all cols identical
    float inv[2][4];
#pragma unroll
    for (int qg = 0; qg < 2; qg++)
#pragma unroll
        for (int r = 0; r < 4; r++)
            inv[qg][r] = 1.f / o_sum[qg][r];
#pragma unroll
    for (int ch = 0; ch < 4; ch++)
#pragma unroll
        for (int qg = 0; qg < 2; qg++)
#pragma unroll
            for (int r = 0; r < 4; r++) {
                long row = qrow0 + qg * 16 + hi * 4 + r;
                Yo[row * 1024 + h * 64 + ch * 16 + lo] =
                    f2b(o_acc[ch][qg][r] * inv[qg][r]);
            }
}

extern "C" void kernel_launch(void* const* d_in, const int* in_sizes, int n_in,
                              void* d_out, int out_size, void* d_ws, size_t ws_size,
                              hipStream_t stream) {
    const float* x = (const float*)d_in[0];
    const float* y = (const float*)d_in[1];
    const float* Wq = (const float*)d_in[2];
    const float* Wk = (const float*)d_in[3];
    const float* Wv = (const float*)d_in[4];
    float* out = (float*)d_out;

    const long NXD = (long)BATCH * NSEQ * DIM;  // 8388608
    const long WSZ = (long)DIM * DIM;           // 1048576
    ushort_t* xb = (ushort_t*)d_ws;
    ushort_t* yb = xb + NXD;
    ushort_t* wqb = yb + NXD;
    ushort_t* wkb = wqb + WSZ;
    ushort_t* wvb = wkb + WSZ;
    ushort_t* Qb = wvb + WSZ;
    ushort_t* Kbb = Qb + NXD;
    ushort_t* Vtb = Kbb + NXD;
    ushort_t* Yob = Vtb + NXD;
    float* partial = (float*)(Yob + NXD);      // [8][16][1024]
    int* counters = (int*)(partial + 8 * 16 * 1024);  // [64]

    conv_all<<<9728, 256, 0, stream>>>((const float4*)x, (const float4*)y,
                                       (const float4*)Wq, (const float4*)Wk,
                                       (const float4*)Wv, (short8*)xb, (short8*)yb,
                                       (short8*)wqb, (short8*)wkb, (short8*)wvb,
                                       counters);

    // Q = (x Wq^T)/8 * (1/ln2)  [8192 x 1024] bf16 (log2-domain logits)
    gemm_nt<ushort_t, 1, false><<<512, 256, 0, stream>>>(
        xb, wqb, Qb, 0, 0, 0, 0.125f * 1.44269504f, nullptr, nullptr);
    // K = y Wk^T      [8192 x 1024] bf16
    gemm_nt<ushort_t, 1, false><<<512, 256, 0, stream>>>(
        yb, wkb, Kbb, 0, 0, 0, 1.0f, nullptr, nullptr);
    // Vt[b] = Wv y[b]^T  -> [B][D][Ny] bf16
    gemm_nt<ushort_t, 2, false><<<512, 256, 0, stream>>>(
        wvb, yb, Vtb, 0, WSZ, WSZ, 1.0f, nullptr, nullptr);
    // fused per-head attention -> y_ [B*Nx, D] bf16
    flash_attn<<<1024, 256, 0, stream>>>(Qb, Kbb, Vtb, Yob);
    // out = softmax_q( x y_^T / 8 ): exp2 + intra-XCD group sync + normalize, one pass
    gemm_nt<float, 3, true><<<512, 256, 0, stream>>>(
        xb, Yob, out, WSZ, WSZ, WSZ, 0.125f * 1.44269504f, partial, counters);
}

// Round 11
// 271.749 us; speedup vs baseline: 1.2302x; 1.2302x over previous
//
#include <hip/hip_runtime.h>

typedef unsigned short ushort_t;
typedef __attribute__((ext_vector_type(8))) short short8;
typedef __attribute__((ext_vector_type(4))) float f32x4;
typedef __attribute__((ext_vector_type(2))) unsigned uint2v;
typedef __attribute__((ext_vector_type(4))) unsigned uint4v;

#define DIM 1024
#define BATCH 8
#define NSEQ 1024
#define HEADS 16
#define HD 64

__device__ __forceinline__ ushort_t f2b(float f) {
    union { float f; unsigned u; } v; v.f = f;
    unsigned r = v.u + 0x7FFF + ((v.u >> 16) & 1);
    return (ushort_t)(r >> 16);
}

__device__ __forceinline__ unsigned cvtpk_bf16(float a, float b) {
    unsigned r;
    asm("v_cvt_pk_bf16_f32 %0, %1, %2" : "=v"(r) : "v"(a), "v"(b));
    return r;
}

__device__ __forceinline__ void g2l16(const void* g, void* l) {
    __builtin_amdgcn_global_load_lds(
        (const __attribute__((address_space(1))) void*)g,
        (__attribute__((address_space(3))) void*)l, 16, 0, 0);
}

// ---------------- fp32 -> bf16 convert, all 5 tensors in one launch ----------------
__global__ __launch_bounds__(256) void conv_all(const float4* __restrict__ x,
                                                const float4* __restrict__ y,
                                                const float4* __restrict__ wq,
                                                const float4* __restrict__ wk,
                                                const float4* __restrict__ wv,
                                                short8* __restrict__ xb,
                                                short8* __restrict__ yb,
                                                short8* __restrict__ wqb,
                                                short8* __restrict__ wkb,
                                                short8* __restrict__ wvb) {
    int j = blockIdx.x;
    const float4* src; short8* dst; int base;
    if (j < 4096)      { src = x;  dst = xb;  base = j; }
    else if (j < 8192) { src = y;  dst = yb;  base = j - 4096; }
    else if (j < 8704) { src = wq; dst = wqb; base = j - 8192; }
    else if (j < 9216) { src = wk; dst = wkb; base = j - 8704; }
    else               { src = wv; dst = wvb; base = j - 9216; }
    int i = base * 256 + threadIdx.x;
    float4 a = src[i * 2], b = src[i * 2 + 1];
    short8 o;
    o[0] = (short)f2b(a.x); o[1] = (short)f2b(a.y);
    o[2] = (short)f2b(a.z); o[3] = (short)f2b(a.w);
    o[4] = (short)f2b(b.x); o[5] = (short)f2b(b.y);
    o[6] = (short)f2b(b.z); o[7] = (short)f2b(b.w);
    dst[i] = o;
}

// -------- fused Q/K/Vt projection GEMMs: one 1536-block launch (bf16 out) --------
// j<512: Q = (x Wq^T)*qscale (MODE1 decode); j<1024: K = y Wk^T; else Vt[b]=Wv y_b^T.
// Sub-grids of 512 keep XCD grouping (512%8==0). 6 blocks/CU queued -> phase overlap.
__global__ __launch_bounds__(256) void qkv_gemm(const ushort_t* __restrict__ xb,
                                                const ushort_t* __restrict__ yb,
                                                const ushort_t* __restrict__ wqb,
                                                const ushort_t* __restrict__ wkb,
                                                const ushort_t* __restrict__ wvb,
                                                ushort_t* __restrict__ Qb,
                                                ushort_t* __restrict__ Kbb,
                                                ushort_t* __restrict__ Vtb,
                                                float qscale) {
    __shared__ __align__(16) ushort_t As[128 * 64];
    __shared__ __align__(16) ushort_t Bs[128 * 64];
    const int tid = threadIdx.x;
    const int w = tid >> 6, l = tid & 63;
    const int wm = w >> 1, wn = w & 1;
    const int lo = l & 15, hi = l >> 4;

    const int j = blockIdx.x;
    const ushort_t *A, *B;
    ushort_t* C;
    int bx, by;
    long aoff = 0, boff = 0, coff = 0;
    float scale;
    if (j < 512) {
        A = xb; B = wqb; C = Qb; by = j & 63; bx = j >> 6; scale = qscale;
    } else if (j < 1024) {
        int i = j - 512;
        A = yb; B = wkb; C = Kbb; by = i & 63; bx = i >> 6; scale = 1.0f;
    } else {
        int i = j - 1024;
        A = wvb; B = yb; C = Vtb; bx = i & 7; by = (i >> 3) & 7;
        int bz = i >> 6;
        boff = (long)bz * 1024 * 1024; coff = (long)bz * 1024 * 1024;
        scale = 1.0f;
    }

    const long abase = (long)by * 128 * 1024 + aoff;
    const long bbase = (long)bx * 128 * 1024 + boff;
    const char* Abytes = (const char*)A;
    const char* Bbytes = (const char*)B;

    f32x4 acc[4][4];
#pragma unroll
    for (int m = 0; m < 4; m++)
#pragma unroll
        for (int n = 0; n < 4; n++) acc[m][n] = (f32x4)0.f;

    for (int kt = 0; kt < 1024; kt += 64) {
#pragma unroll
        for (int i = 0; i < 4; i++) {
            int o16 = tid + i * 256;
            int row = o16 >> 3;
            int cb = (o16 & 7) * 16;
            int scb = cb ^ ((row & 7) << 4);
            g2l16(Abytes + (abase + (long)row * 1024 + kt) * 2 + scb,
                  (char*)As + o16 * 16);
            g2l16(Bbytes + (bbase + (long)row * 1024 + kt) * 2 + scb,
                  (char*)Bs + o16 * 16);
        }
        __syncthreads();
#pragma unroll
        for (int kc = 0; kc < 2; kc++) {
            short8 af[4], bfr[4];
#pragma unroll
            for (int m = 0; m < 4; m++) {
                int row = wm * 64 + m * 16 + lo;
                int cb = (kc * 64 + hi * 16) ^ ((row & 7) << 4);
                af[m] = *(const short8*)((const char*)As + row * 128 + cb);
            }
#pragma unroll
            for (int n = 0; n < 4; n++) {
                int row = wn * 64 + n * 16 + lo;
                int cb = (kc * 64 + hi * 16) ^ ((row & 7) << 4);
                bfr[n] = *(const short8*)((const char*)Bs + row * 128 + cb);
            }
            __builtin_amdgcn_s_setprio(1);
#pragma unroll
            for (int m = 0; m < 4; m++)
#pragma unroll
                for (int n = 0; n < 4; n++)
                    acc[m][n] = __builtin_amdgcn_mfma_f32_16x16x32_bf16(
                        af[m], bfr[n], acc[m][n], 0, 0, 0);
            __builtin_amdgcn_s_setprio(0);
        }
        __syncthreads();
    }

#pragma unroll
    for (int m = 0; m < 4; m++)
#pragma unroll
        for (int n = 0; n < 4; n++)
#pragma unroll
            for (int r = 0; r < 4; r++) {
                long row = (long)by * 128 + wm * 64 + m * 16 + hi * 4 + r;
                long col = (long)bx * 128 + wn * 64 + n * 16 + lo;
                C[coff + row * 1024 + col] = f2b(acc[m][n][r] * scale);
            }
}

// ------------- s-GEMM: out = exp2(x y_^T * scale) + per-column partials -------------
// MODE3 decode (bz=j&7 -> XCD = batch). One dispatch, 512 blocks.
__global__ __launch_bounds__(256) void s_gemm(const ushort_t* __restrict__ A,
                                              const ushort_t* __restrict__ B,
                                              float* __restrict__ C,
                                              float scale,
                                              float* __restrict__ partial) {
    __shared__ __align__(16) ushort_t As[128 * 64];
    __shared__ __align__(16) ushort_t Bs[128 * 64];
    const int tid = threadIdx.x;
    const int w = tid >> 6, l = tid & 63;
    const int wm = w >> 1, wn = w & 1;
    const int lo = l & 15, hi = l >> 4;

    const int j = blockIdx.x;
    const int bz = j & 7, bx = (j >> 3) & 7, by = j >> 6;

    const long abase = (long)by * 128 * 1024 + (long)bz * 1024 * 1024;
    const long bbase = (long)bx * 128 * 1024 + (long)bz * 1024 * 1024;
    const char* Abytes = (const char*)A;
    const char* Bbytes = (const char*)B;

    f32x4 acc[4][4];
#pragma unroll
    for (int m = 0; m < 4; m++)
#pragma unroll
        for (int n = 0; n < 4; n++) acc[m][n] = (f32x4)0.f;

    for (int kt = 0; kt < 1024; kt += 64) {
#pragma unroll
        for (int i = 0; i < 4; i++) {
            int o16 = tid + i * 256;
            int row = o16 >> 3;
            int cb = (o16 & 7) * 16;
            int scb = cb ^ ((row & 7) << 4);
            g2l16(Abytes + (abase + (long)row * 1024 + kt) * 2 + scb,
                  (char*)As + o16 * 16);
            g2l16(Bbytes + (bbase + (long)row * 1024 + kt) * 2 + scb,
                  (char*)Bs + o16 * 16);
        }
        __syncthreads();
#pragma unroll
        for (int kc = 0; kc < 2; kc++) {
            short8 af[4], bfr[4];
#pragma unroll
            for (int m = 0; m < 4; m++) {
                int row = wm * 64 + m * 16 + lo;
                int cb = (kc * 64 + hi * 16) ^ ((row & 7) << 4);
                af[m] = *(const short8*)((const char*)As + row * 128 + cb);
            }
#pragma unroll
            for (int n = 0; n < 4; n++) {
                int row = wn * 64 + n * 16 + lo;
                int cb = (kc * 64 + hi * 16) ^ ((row & 7) << 4);
                bfr[n] = *(const short8*)((const char*)Bs + row * 128 + cb);
            }
            __builtin_amdgcn_s_setprio(1);
#pragma unroll
            for (int m = 0; m < 4; m++)
#pragma unroll
                for (int n = 0; n < 4; n++)
                    acc[m][n] = __builtin_amdgcn_mfma_f32_16x16x32_bf16(
                        af[m], bfr[n], acc[m][n], 0, 0, 0);
            __builtin_amdgcn_s_setprio(0);
        }
        __syncthreads();
    }

    const long cb0 = (long)bz * 1024 * 1024;
#pragma unroll
    for (int n = 0; n < 4; n++) {
        float csum = 0.f;
#pragma unroll
        for (int m = 0; m < 4; m++)
#pragma unroll
            for (int r = 0; r < 4; r++) {
                long row = (long)by * 128 + wm * 64 + m * 16 + hi * 4 + r;
                long col = (long)bx * 128 + wn * 64 + n * 16 + lo;
                float e = exp2f(acc[m][n][r] * scale);
                C[cb0 + row * 1024 + col] = e;
                csum += e;
            }
        csum += __shfl_xor(csum, 16);
        csum += __shfl_xor(csum, 32);
        if (hi == 0)
            partial[((long)bz << 14) + (by * 2 + wm) * 1024 +
                    bx * 128 + wn * 64 + n * 16 + lo] = csum;
    }
}

// ---------------- fused flash attention ----------------
// 4 waves x 32 q = 128 q/block. KV tile 64, double-buffered LDS (32 KB).
// Swapped QK^T; raw exp2 (no max tracking); P in registers via cvt_pk+permlane;
// softmax denominator via ones-MFMA (row sums land in o_acc's C-layout).
__global__ __launch_bounds__(256, 4) void flash_attn(const ushort_t* __restrict__ Q,
                                                     const ushort_t* __restrict__ Kb,
                                                     const ushort_t* __restrict__ Vt,
                                                     ushort_t* __restrict__ Yo) {
    __shared__ __align__(16) ushort_t Ks[2][64 * 64];   // [key][d], swizzled
    __shared__ __align__(16) ushort_t Vs[2][64 * 64];   // [d][k],  swizzled
    const int j = blockIdx.x;
    const int g = j & 127, qt = j >> 7;
    const int h = g & 15, b = g >> 4;
    const int tid = threadIdx.x, w = tid >> 6, l = tid & 63;
    const int lo = l & 15, hi = l >> 4;
    const int sw = (lo & 7) << 4;  // K/V row swizzle (128B rows)

    const char* Khb = (const char*)(Kb + (long)b * 1024 * 1024 + h * 64);
    const char* Vhb = (const char*)(Vt + (long)b * 1024 * 1024 + (long)h * 64 * 1024);

    const long qrow0 = (long)b * 1024 + qt * 128 + w * 32;
    short8 qf[2][2];
#pragma unroll
    for (int qg = 0; qg < 2; qg++)
#pragma unroll
        for (int dk = 0; dk < 2; dk++)
            qf[qg][dk] = *(const short8*)(Q + (qrow0 + qg * 16 + lo) * 1024 +
                                          h * 64 + dk * 32 + hi * 8);

    short8 ones;
#pragma unroll
    for (int i = 0; i < 8; i++) ones[i] = (short)0x3F80;  // bf16 1.0

    f32x4 o_acc[4][2], o_sum[2];
#pragma unroll
    for (int ch = 0; ch < 4; ch++)
#pragma unroll
        for (int qg = 0; qg < 2; qg++) o_acc[ch][qg] = (f32x4)0.f;
    o_sum[0] = (f32x4)0.f; o_sum[1] = (f32x4)0.f;

    {
#pragma unroll
        for (int i = 0; i < 2; i++) {
            int o16 = tid + i * 256;
            int row = o16 >> 3, cb = (o16 & 7) * 16;
            int scb = cb ^ ((row & 7) << 4);
            g2l16(Khb + (long)row * 2048 + scb, (char*)Ks[0] + o16 * 16);
            g2l16(Vhb + (long)row * 2048 + scb, (char*)Vs[0] + o16 * 16);
        }
    }

    for (int t = 0; t < 16; t++) {
        __syncthreads();
        if (t < 15) {
            int kt = (t + 1) * 64;
            int bufn = (t + 1) & 1;
#pragma unroll
            for (int i = 0; i < 2; i++) {
                int o16 = tid + i * 256;
                int row = o16 >> 3, cb = (o16 & 7) * 16;
                int scb = cb ^ ((row & 7) << 4);
                g2l16(Khb + ((long)(kt + row) * 1024) * 2 + scb,
                      (char*)Ks[bufn] + o16 * 16);
                g2l16(Vhb + ((long)row * 1024 + kt) * 2 + scb,
                      (char*)Vs[bufn] + o16 * 16);
            }
        }
        const char* Kc = (const char*)Ks[t & 1];
        const char* Vc = (const char*)Vs[t & 1];

        // QK^T swapped: s_acc[ks][qg][r] = S[key=ks*16+hi*4+r][q=qg*16+lo] (log2 units)
        f32x4 s_acc[4][2];
        __builtin_amdgcn_s_setprio(1);
#pragma unroll
        for (int ks = 0; ks < 4; ks++) {
            const char* kr = Kc + (ks * 16 + lo) * 128;
            short8 kf0 = *(const short8*)(kr + ((hi * 16) ^ sw));
            short8 kf1 = *(const short8*)(kr + ((64 + hi * 16) ^ sw));
#pragma unroll
            for (int qg = 0; qg < 2; qg++) {
                s_acc[ks][qg] = __builtin_amdgcn_mfma_f32_16x16x32_bf16(
                    kf0, qf[qg][0], (f32x4)0.f, 0, 0, 0);
                s_acc[ks][qg] = __builtin_amdgcn_mfma_f32_16x16x32_bf16(
                    kf1, qf[qg][1], s_acc[ks][qg], 0, 0, 0);
            }
        }
        __builtin_amdgcn_s_setprio(0);

        // p = exp2(s) raw; pack to bf16 words (denominator comes from ones-MFMA)
        unsigned pk[2][4][2];  // [qg][ks][r2]
#pragma unroll
        for (int qg = 0; qg < 2; qg++)
#pragma unroll
            for (int ks = 0; ks < 4; ks++) {
#pragma unroll
                for (int r = 0; r < 4; r++)
                    s_acc[ks][qg][r] = exp2f(s_acc[ks][qg][r]);
                pk[qg][ks][0] = cvtpk_bf16(s_acc[ks][qg][0], s_acc[ks][qg][1]);
                pk[qg][ks][1] = cvtpk_bf16(s_acc[ks][qg][2], s_acc[ks][qg][3]);
            }

        // PV: redistribute P across hi-groups in-register, then MFMA (+ row sums).
#pragma unroll
        for (int kk = 0; kk < 2; kk++) {
            short8 pa[2];
#pragma unroll
            for (int qg = 0; qg < 2; qg++) {
                unsigned a0 = pk[qg][2 * kk][0], b0 = pk[qg][2 * kk + 1][0];
                uint2v t0 = __builtin_amdgcn_permlane32_swap(a0, b0, false, false);
                t0 = __builtin_amdgcn_permlane16_swap(t0[0], t0[1], false, false);
                unsigned a1 = pk[qg][2 * kk][1], b1 = pk[qg][2 * kk + 1][1];
                uint2v t1 = __builtin_amdgcn_permlane32_swap(a1, b1, false, false);
                t1 = __builtin_amdgcn_permlane16_swap(t1[0], t1[1], false, false);
                union { uint4v u; short8 s; } cv;
                cv.u = (uint4v){t0[0], t1[0], t0[1], t1[1]};
                pa[qg] = cv.s;
            }
            __builtin_amdgcn_s_setprio(1);
#pragma unroll
            for (int qg = 0; qg < 2; qg++)
                o_sum[qg] = __builtin_amdgcn_mfma_f32_16x16x32_bf16(
                    pa[qg], ones, o_sum[qg], 0, 0, 0);
#pragma unroll
            for (int ch = 0; ch < 4; ch++) {
                short8 vf = *(const short8*)(Vc + (ch * 16 + lo) * 128 +
                                             ((kk * 64 + hi * 16) ^ sw));
#pragma unroll
                for (int qg = 0; qg < 2; qg++)
                    o_acc[ch][qg] = __builtin_amdgcn_mfma_f32_16x16x32_bf16(
                        pa[qg], vf, o_acc[ch][qg], 0, 0, 0);
            }
            __builtin_amdgcn_s_setprio(0);
        }
    }

    // epilogue: o_sum already in C-layout per (qg, hi*4+r); all cols identical
    float inv[2][4];
#pragma unroll
    for (int qg = 0; qg < 2; qg++)
#pragma unroll
        for (int r = 0; r < 4; r++)
            inv[qg][r] = 1.f / o_sum[qg][r];
#pragma unroll
    for (int ch = 0; ch < 4; ch++)
#pragma unroll
        for (int qg = 0; qg < 2; qg++)
#pragma unroll
            for (int r = 0; r < 4; r++) {
                long row = qrow0 + qg * 16 + hi * 4 + r;
                Yo[row * 1024 + h * 64 + ch * 16 + lo] =
                    f2b(o_acc[ch][qg][r] * inv[qg][r]);
            }
}

// ---------------- column-sum inverse: inv[b][c] = 1 / sum_k partial[b][k][c] ----
__global__ __launch_bounds__(256) void colsum_inv(const float* __restrict__ partial,
                                                  float* __restrict__ inv) {
    int i = blockIdx.x * 256 + threadIdx.x;  // 8192 = b*1024 + c
    int b = i >> 10, c = i & 1023;
    const float* p = partial + ((long)b << 14) + c;
    float s = 0.f;
#pragma unroll
    for (int k = 0; k < 16; k++) s += p[k * 1024];
    inv[i] = 1.f / s;
}

// ---------------- scale rows: S[b][r][c] *= inv[b][c] (S holds exp values) ----
__global__ __launch_bounds__(256) void scale_rows(float4* __restrict__ S,
                                                  const float4* __restrict__ inv) {
    long i = (long)blockIdx.x * 256 + threadIdx.x;  // f4 index, 2097152 total
    int c4 = (int)(i & 255);
    int b = (int)(i >> 18);
    float4 v = S[i];
    float4 iv = inv[b * 256 + c4];
    v.x *= iv.x; v.y *= iv.y; v.z *= iv.z; v.w *= iv.w;
    S[i] = v;
}

extern "C" void kernel_launch(void* const* d_in, const int* in_sizes, int n_in,
                              void* d_out, int out_size, void* d_ws, size_t ws_size,
                              hipStream_t stream) {
    const float* x = (const float*)d_in[0];
    const float* y = (const float*)d_in[1];
    const float* Wq = (const float*)d_in[2];
    const float* Wk = (const float*)d_in[3];
    const float* Wv = (const float*)d_in[4];
    float* out = (float*)d_out;

    const long NXD = (long)BATCH * NSEQ * DIM;  // 8388608
    const long WSZ = (long)DIM * DIM;           // 1048576
    ushort_t* xb = (ushort_t*)d_ws;
    ushort_t* yb = xb + NXD;
    ushort_t* wqb = yb + NXD;
    ushort_t* wkb = wqb + WSZ;
    ushort_t* wvb = wkb + WSZ;
    ushort_t* Qb = wvb + WSZ;
    ushort_t* Kbb = Qb + NXD;
    ushort_t* Vtb = Kbb + NXD;
    ushort_t* Yob = Vtb + NXD;
    float* partial = (float*)(Yob + NXD);     // [8][16][1024]
    float* invcol = partial + 8 * 16 * 1024;  // [8][1024]

    conv_all<<<9728, 256, 0, stream>>>((const float4*)x, (const float4*)y,
                                       (const float4*)Wq, (const float4*)Wk,
                                       (const float4*)Wv, (short8*)xb, (short8*)yb,
                                       (short8*)wqb, (short8*)wkb, (short8*)wvb);

    // fused projections: Q=(x Wq^T)*0.125/ln2 (log2-domain), K=y Wk^T, Vt[b]=Wv y_b^T
    qkv_gemm<<<1536, 256, 0, stream>>>(xb, yb, wqb, wkb, wvb, Qb, Kbb, Vtb,
                                       0.125f * 1.44269504f);
    // fused per-head attention -> y_ [B*Nx, D] bf16
    flash_attn<<<1024, 256, 0, stream>>>(Qb, Kbb, Vtb, Yob);
    // out = exp2(x y_^T * 0.125/ln2) + per-column partial sums
    s_gemm<<<512, 256, 0, stream>>>(xb, Yob, out, 0.125f * 1.44269504f, partial);
    // inv column sums, then scale -> softmax over q (dim=-2)
    colsum_inv<<<32, 256, 0, stream>>>(partial, invcol);
    scale_rows<<<8192, 256, 0, stream>>>((float4*)out, (const float4*)invcol);
}

// Round 13
// 248.263 us; speedup vs baseline: 1.3466x; 1.0946x over previous
//
#include <hip/hip_runtime.h>

typedef unsigned short ushort_t;
typedef __attribute__((ext_vector_type(8))) short short8;
typedef __attribute__((ext_vector_type(4))) float f32x4;
typedef __attribute__((ext_vector_type(2))) unsigned uint2v;
typedef __attribute__((ext_vector_type(4))) unsigned uint4v;

#define DIM 1024
#define BATCH 8
#define NSEQ 1024
#define HEADS 16
#define HD 64

__device__ __forceinline__ ushort_t f2b(float f) {
    union { float f; unsigned u; } v; v.f = f;
    unsigned r = v.u + 0x7FFF + ((v.u >> 16) & 1);
    return (ushort_t)(r >> 16);
}

__device__ __forceinline__ unsigned cvtpk_bf16(float a, float b) {
    unsigned r;
    asm("v_cvt_pk_bf16_f32 %0, %1, %2" : "=v"(r) : "v"(a), "v"(b));
    return r;
}

// single-instruction 2^x (no libm fixup path; inputs bounded)
__device__ __forceinline__ float fexp2(float x) {
    float r;
    asm("v_exp_f32 %0, %1" : "=v"(r) : "v"(x));
    return r;
}

__device__ __forceinline__ void g2l16(const void* g, void* l) {
    __builtin_amdgcn_global_load_lds(
        (const __attribute__((address_space(1))) void*)g,
        (__attribute__((address_space(3))) void*)l, 16, 0, 0);
}

// ---------------- fp32 -> bf16 convert, all 5 tensors in one launch ----------------
__global__ __launch_bounds__(256) void conv_all(const float4* __restrict__ x,
                                                const float4* __restrict__ y,
                                                const float4* __restrict__ wq,
                                                const float4* __restrict__ wk,
                                                const float4* __restrict__ wv,
                                                short8* __restrict__ xb,
                                                short8* __restrict__ yb,
                                                short8* __restrict__ wqb,
                                                short8* __restrict__ wkb,
                                                short8* __restrict__ wvb) {
    int j = blockIdx.x;
    const float4* src; short8* dst; int base;
    if (j < 4096)      { src = x;  dst = xb;  base = j; }
    else if (j < 8192) { src = y;  dst = yb;  base = j - 4096; }
    else if (j < 8704) { src = wq; dst = wqb; base = j - 8192; }
    else if (j < 9216) { src = wk; dst = wkb; base = j - 8704; }
    else               { src = wv; dst = wvb; base = j - 9216; }
    int i = base * 256 + threadIdx.x;
    float4 a = src[i * 2], b = src[i * 2 + 1];
    short8 o;
    o[0] = (short)f2b(a.x); o[1] = (short)f2b(a.y);
    o[2] = (short)f2b(a.z); o[3] = (short)f2b(a.w);
    o[4] = (short)f2b(b.x); o[5] = (short)f2b(b.y);
    o[6] = (short)f2b(b.z); o[7] = (short)f2b(b.w);
    dst[i] = o;
}

// -------- fused Q/K/Vt projection GEMMs: one 1536-block launch (bf16 out) --------
__global__ __launch_bounds__(256) void qkv_gemm(const ushort_t* __restrict__ xb,
                                                const ushort_t* __restrict__ yb,
                                                const ushort_t* __restrict__ wqb,
                                                const ushort_t* __restrict__ wkb,
                                                const ushort_t* __restrict__ wvb,
                                                ushort_t* __restrict__ Qb,
                                                ushort_t* __restrict__ Kbb,
                                                ushort_t* __restrict__ Vtb,
                                                float qscale) {
    __shared__ __align__(16) ushort_t As[128 * 64];
    __shared__ __align__(16) ushort_t Bs[128 * 64];
    const int tid = threadIdx.x;
    const int w = tid >> 6, l = tid & 63;
    const int wm = w >> 1, wn = w & 1;
    const int lo = l & 15, hi = l >> 4;

    const int j = blockIdx.x;
    const ushort_t *A, *B;
    ushort_t* C;
    int bx, by;
    long aoff = 0, boff = 0, coff = 0;
    float scale;
    if (j < 512) {
        A = xb; B = wqb; C = Qb; by = j & 63; bx = j >> 6; scale = qscale;
    } else if (j < 1024) {
        int i = j - 512;
        A = yb; B = wkb; C = Kbb; by = i & 63; bx = i >> 6; scale = 1.0f;
    } else {
        int i = j - 1024;
        A = wvb; B = yb; C = Vtb; bx = i & 7; by = (i >> 3) & 7;
        int bz = i >> 6;
        boff = (long)bz * 1024 * 1024; coff = (long)bz * 1024 * 1024;
        scale = 1.0f;
    }

    const long abase = (long)by * 128 * 1024 + aoff;
    const long bbase = (long)bx * 128 * 1024 + boff;
    const char* Abytes = (const char*)A;
    const char* Bbytes = (const char*)B;

    f32x4 acc[4][4];
#pragma unroll
    for (int m = 0; m < 4; m++)
#pragma unroll
        for (int n = 0; n < 4; n++) acc[m][n] = (f32x4)0.f;

    for (int kt = 0; kt < 1024; kt += 64) {
#pragma unroll
        for (int i = 0; i < 4; i++) {
            int o16 = tid + i * 256;
            int row = o16 >> 3;
            int cb = (o16 & 7) * 16;
            int scb = cb ^ ((row & 7) << 4);
            g2l16(Abytes + (abase + (long)row * 1024 + kt) * 2 + scb,
                  (char*)As + o16 * 16);
            g2l16(Bbytes + (bbase + (long)row * 1024 + kt) * 2 + scb,
                  (char*)Bs + o16 * 16);
        }
        __syncthreads();
#pragma unroll
        for (int kc = 0; kc < 2; kc++) {
            short8 af[4], bfr[4];
#pragma unroll
            for (int m = 0; m < 4; m++) {
                int row = wm * 64 + m * 16 + lo;
                int cb = (kc * 64 + hi * 16) ^ ((row & 7) << 4);
                af[m] = *(const short8*)((const char*)As + row * 128 + cb);
            }
#pragma unroll
            for (int n = 0; n < 4; n++) {
                int row = wn * 64 + n * 16 + lo;
                int cb = (kc * 64 + hi * 16) ^ ((row & 7) << 4);
                bfr[n] = *(const short8*)((const char*)Bs + row * 128 + cb);
            }
            __builtin_amdgcn_s_setprio(1);
#pragma unroll
            for (int m = 0; m < 4; m++)
#pragma unroll
                for (int n = 0; n < 4; n++)
                    acc[m][n] = __builtin_amdgcn_mfma_f32_16x16x32_bf16(
                        af[m], bfr[n], acc[m][n], 0, 0, 0);
            __builtin_amdgcn_s_setprio(0);
        }
        __syncthreads();
    }

#pragma unroll
    for (int m = 0; m < 4; m++)
#pragma unroll
        for (int n = 0; n < 4; n++)
#pragma unroll
            for (int r = 0; r < 4; r++) {
                long row = (long)by * 128 + wm * 64 + m * 16 + hi * 4 + r;
                long col = (long)bx * 128 + wn * 64 + n * 16 + lo;
                C[coff + row * 1024 + col] = f2b(acc[m][n][r] * scale);
            }
}

// ------------- s-GEMM: out = exp2(x y_^T * scale) + per-column partials -------------
__global__ __launch_bounds__(256) void s_gemm(const ushort_t* __restrict__ A,
                                              const ushort_t* __restrict__ B,
                                              float* __restrict__ C,
                                              float scale,
                                              float* __restrict__ partial) {
    __shared__ __align__(16) ushort_t As[128 * 64];
    __shared__ __align__(16) ushort_t Bs[128 * 64];
    const int tid = threadIdx.x;
    const int w = tid >> 6, l = tid & 63;
    const int wm = w >> 1, wn = w & 1;
    const int lo = l & 15, hi = l >> 4;

    const int j = blockIdx.x;
    const int bz = j & 7, bx = (j >> 3) & 7, by = j >> 6;

    const long abase = (long)by * 128 * 1024 + (long)bz * 1024 * 1024;
    const long bbase = (long)bx * 128 * 1024 + (long)bz * 1024 * 1024;
    const char* Abytes = (const char*)A;
    const char* Bbytes = (const char*)B;

    f32x4 acc[4][4];
#pragma unroll
    for (int m = 0; m < 4; m++)
#pragma unroll
        for (int n = 0; n < 4; n++) acc[m][n] = (f32x4)0.f;

    for (int kt = 0; kt < 1024; kt += 64) {
#pragma unroll
        for (int i = 0; i < 4; i++) {
            int o16 = tid + i * 256;
            int row = o16 >> 3;
            int cb = (o16 & 7) * 16;
            int scb = cb ^ ((row & 7) << 4);
            g2l16(Abytes + (abase + (long)row * 1024 + kt) * 2 + scb,
                  (char*)As + o16 * 16);
            g2l16(Bbytes + (bbase + (long)row * 1024 + kt) * 2 + scb,
                  (char*)Bs + o16 * 16);
        }
        __syncthreads();
#pragma unroll
        for (int kc = 0; kc < 2; kc++) {
            short8 af[4], bfr[4];
#pragma unroll
            for (int m = 0; m < 4; m++) {
                int row = wm * 64 + m * 16 + lo;
                int cb = (kc * 64 + hi * 16) ^ ((row & 7) << 4);
                af[m] = *(const short8*)((const char*)As + row * 128 + cb);
            }
#pragma unroll
            for (int n = 0; n < 4; n++) {
                int row = wn * 64 + n * 16 + lo;
                int cb = (kc * 64 + hi * 16) ^ ((row & 7) << 4);
                bfr[n] = *(const short8*)((const char*)Bs + row * 128 + cb);
            }
            __builtin_amdgcn_s_setprio(1);
#pragma unroll
            for (int m = 0; m < 4; m++)
#pragma unroll
                for (int n = 0; n < 4; n++)
                    acc[m][n] = __builtin_amdgcn_mfma_f32_16x16x32_bf16(
                        af[m], bfr[n], acc[m][n], 0, 0, 0);
            __builtin_amdgcn_s_setprio(0);
        }
        __syncthreads();
    }

    const long cb0 = (long)bz * 1024 * 1024;
#pragma unroll
    for (int n = 0; n < 4; n++) {
        float csum = 0.f;
#pragma unroll
        for (int m = 0; m < 4; m++)
#pragma unroll
            for (int r = 0; r < 4; r++) {
                long row = (long)by * 128 + wm * 64 + m * 16 + hi * 4 + r;
                long col = (long)bx * 128 + wn * 64 + n * 16 + lo;
                float e = fexp2(acc[m][n][r] * scale);
                C[cb0 + row * 1024 + col] = e;
                csum += e;
            }
        csum += __shfl_xor(csum, 16);
        csum += __shfl_xor(csum, 32);
        if (hi == 0)
            partial[((long)bz << 14) + (by * 2 + wm) * 1024 +
                    bx * 128 + wn * 64 + n * 16 + lo] = csum;
    }
}

// ---------------- fused flash attention ----------------
// 4 waves x 32 q = 128 q/block. KV tile 64, double-buffered LDS (32 KB).
// Swapped QK^T; raw v_exp_f32 (log2 domain, no max tracking); P in registers via
// cvt_pk+permlane; softmax denominator via ones-MFMA.
__global__ __launch_bounds__(256, 4) void flash_attn(const ushort_t* __restrict__ Q,
                                                     const ushort_t* __restrict__ Kb,
                                                     const ushort_t* __restrict__ Vt,
                                                     ushort_t* __restrict__ Yo) {
    __shared__ __align__(16) ushort_t Ks[2][64 * 64];   // [key][d], swizzled
    __shared__ __align__(16) ushort_t Vs[2][64 * 64];   // [d][k],  swizzled
    const int j = blockIdx.x;
    const int g = j & 127, qt = j >> 7;
    const int h = g & 15, b = g >> 4;
    const int tid = threadIdx.x, w = tid >> 6, l = tid & 63;
    const int lo = l & 15, hi = l >> 4;
    const int sw = (lo & 7) << 4;  // K/V row swizzle (128B rows)

    const char* Khb = (const char*)(Kb + (long)b * 1024 * 1024 + h * 64);
    const char* Vhb = (const char*)(Vt + (long)b * 1024 * 1024 + (long)h * 64 * 1024);

    const long qrow0 = (long)b * 1024 + qt * 128 + w * 32;
    short8 qf[2][2];
#pragma unroll
    for (int qg = 0; qg < 2; qg++)
#pragma unroll
        for (int dk = 0; dk < 2; dk++)
            qf[qg][dk] = *(const short8*)(Q + (qrow0 + qg * 16 + lo) * 1024 +
                                          h * 64 + dk * 32 + hi * 8);

    short8 ones;
#pragma unroll
    for (int i = 0; i < 8; i++) ones[i] = (short)0x3F80;  // bf16 1.0

    f32x4 o_acc[4][2], o_sum[2];
#pragma unroll
    for (int ch = 0; ch < 4; ch++)
#pragma unroll
        for (int qg = 0; qg < 2; qg++) o_acc[ch][qg] = (f32x4)0.f;
    o_sum[0] = (f32x4)0.f; o_sum[1] = (f32x4)0.f;

    {
#pragma unroll
        for (int i = 0; i < 2; i++) {
            int o16 = tid + i * 256;
            int row = o16 >> 3, cb = (o16 & 7) * 16;
            int scb = cb ^ ((row & 7) << 4);
            g2l16(Khb + (long)row * 2048 + scb, (char*)Ks[0] + o16 * 16);
            g2l16(Vhb + (long)row * 2048 + scb, (char*)Vs[0] + o16 * 16);
        }
    }

    for (int t = 0; t < 16; t++) {
        __syncthreads();
        if (t < 15) {
            int kt = (t + 1) * 64;
            int bufn = (t + 1) & 1;
#pragma unroll
            for (int i = 0; i < 2; i++) {
                int o16 = tid + i * 256;
                int row = o16 >> 3, cb = (o16 & 7) * 16;
                int scb = cb ^ ((row & 7) << 4);
                g2l16(Khb + ((long)(kt + row) * 1024) * 2 + scb,
                      (char*)Ks[bufn] + o16 * 16);
                g2l16(Vhb + ((long)row * 1024 + kt) * 2 + scb,
                      (char*)Vs[bufn] + o16 * 16);
            }
        }
        const char* Kc = (const char*)Ks[t & 1];
        const char* Vc = (const char*)Vs[t & 1];

        // QK^T swapped: s_acc[ks][qg][r] = S[key=ks*16+hi*4+r][q=qg*16+lo] (log2 units)
        f32x4 s_acc[4][2];
        __builtin_amdgcn_s_setprio(1);
#pragma unroll
        for (int ks = 0; ks < 4; ks++) {
            const char* kr = Kc + (ks * 16 + lo) * 128;
            short8 kf0 = *(const short8*)(kr + ((hi * 16) ^ sw));
            short8 kf1 = *(const short8*)(kr + ((64 + hi * 16) ^ sw));
#pragma unroll
            for (int qg = 0; qg < 2; qg++) {
                s_acc[ks][qg] = __builtin_amdgcn_mfma_f32_16x16x32_bf16(
                    kf0, qf[qg][0], (f32x4)0.f, 0, 0, 0);
                s_acc[ks][qg] = __builtin_amdgcn_mfma_f32_16x16x32_bf16(
                    kf1, qf[qg][1], s_acc[ks][qg], 0, 0, 0);
            }
        }
        __builtin_amdgcn_s_setprio(0);

        // p = 2^s raw (single v_exp_f32 each); pack to bf16 words
        unsigned pk[2][4][2];  // [qg][ks][r2]
#pragma unroll
        for (int qg = 0; qg < 2; qg++)
#pragma unroll
            for (int ks = 0; ks < 4; ks++) {
#pragma unroll
                for (int r = 0; r < 4; r++)
                    s_acc[ks][qg][r] = fexp2(s_acc[ks][qg][r]);
                pk[qg][ks][0] = cvtpk_bf16(s_acc[ks][qg][0], s_acc[ks][qg][1]);
                pk[qg][ks][1] = cvtpk_bf16(s_acc[ks][qg][2], s_acc[ks][qg][3]);
            }

        // PV: redistribute P across hi-groups in-register, then MFMA (+ row sums).
#pragma unroll
        for (int kk = 0; kk < 2; kk++) {
            short8 pa[2];
#pragma unroll
            for (int qg = 0; qg < 2; qg++) {
                unsigned a0 = pk[qg][2 * kk][0], b0 = pk[qg][2 * kk + 1][0];
                uint2v t0 = __builtin_amdgcn_permlane32_swap(a0, b0, false, false);
                t0 = __builtin_amdgcn_permlane16_swap(t0[0], t0[1], false, false);
                unsigned a1 = pk[qg][2 * kk][1], b1 = pk[qg][2 * kk + 1][1];
                uint2v t1 = __builtin_amdgcn_permlane32_swap(a1, b1, false, false);
                t1 = __builtin_amdgcn_permlane16_swap(t1[0], t1[1], false, false);
                union { uint4v u; short8 s; } cv;
                cv.u = (uint4v){t0[0], t1[0], t0[1], t1[1]};
                pa[qg] = cv.s;
            }
            __builtin_amdgcn_s_setprio(1);
#pragma unroll
            for (int qg = 0; qg < 2; qg++)
                o_sum[qg] = __builtin_amdgcn_mfma_f32_16x16x32_bf16(
                    pa[qg], ones, o_sum[qg], 0, 0, 0);
#pragma unroll
            for (int ch = 0; ch < 4; ch++) {
                short8 vf = *(const short8*)(Vc + (ch * 16 + lo) * 128 +
                                             ((kk * 64 + hi * 16) ^ sw));
#pragma unroll
                for (int qg = 0; qg < 2; qg++)
                    o_acc[ch][qg] = __builtin_amdgcn_mfma_f32_16x16x32_bf16(
                        pa[qg], vf, o_acc[ch][qg], 0, 0, 0);
            }
            __builtin_amdgcn_s_setprio(0);
        }
    }

    // epilogue: o_sum already in C-layout per (qg, hi*4+r); all cols identical
    float inv[2][4];
#pragma unroll
    for (int qg = 0; qg < 2; qg++)
#pragma unroll
        for (int r = 0; r < 4; r++)
            inv[qg][r] = 1.f / o_sum[qg][r];
#pragma unroll
    for (int ch = 0; ch < 4; ch++)
#pragma unroll
        for (int qg = 0; qg < 2; qg++)
#pragma unroll
            for (int r = 0; r < 4; r++) {
                long row = qrow0 + qg * 16 + hi * 4 + r;
                Yo[row * 1024 + h * 64 + ch * 16 + lo] =
                    f2b(o_acc[ch][qg][r] * inv[qg][r]);
            }
}

// ---------------- column-sum inverse: inv[b][c] = 1 / sum_k partial[b][k][c] ----
__global__ __launch_bounds__(256) void colsum_inv(const float* __restrict__ partial,
                                                  float* __restrict__ inv) {
    int i = blockIdx.x * 256 + threadIdx.x;  // 8192 = b*1024 + c
    int b = i >> 10, c = i & 1023;
    const float* p = partial + ((long)b << 14) + c;
    float s = 0.f;
#pragma unroll
    for (int k = 0; k < 16; k++) s += p[k * 1024];
    inv[i] = 1.f / s;
}

// ---------------- scale rows: S[b][r][c] *= inv[b][c] (S holds exp values) ----
__global__ __launch_bounds__(256) void scale_rows(float4* __restrict__ S,
                                                  const float4* __restrict__ inv) {
    long i = (long)blockIdx.x * 256 + threadIdx.x;  // f4 index, 2097152 total
    int c4 = (int)(i & 255);
    int b = (int)(i >> 18);
    float4 v = S[i];
    float4 iv = inv[b * 256 + c4];
    v.x *= iv.x; v.y *= iv.y; v.z *= iv.z; v.w *= iv.w;
    S[i] = v;
}

extern "C" void kernel_launch(void* const* d_in, const int* in_sizes, int n_in,
                              void* d_out, int out_size, void* d_ws, size_t ws_size,
                              hipStream_t stream) {
    const float* x = (const float*)d_in[0];
    const float* y = (const float*)d_in[1];
    const float* Wq = (const float*)d_in[2];
    const float* Wk = (const float*)d_in[3];
    const float* Wv = (const float*)d_in[4];
    float* out = (float*)d_out;

    const long NXD = (long)BATCH * NSEQ * DIM;  // 8388608
    const long WSZ = (long)DIM * DIM;           // 1048576
    ushort_t* xb = (ushort_t*)d_ws;
    ushort_t* yb = xb + NXD;
    ushort_t* wqb = yb + NXD;
    ushort_t* wkb = wqb + WSZ;
    ushort_t* wvb = wkb + WSZ;
    ushort_t* Qb = wvb + WSZ;
    ushort_t* Kbb = Qb + NXD;
    ushort_t* Vtb = Kbb + NXD;
    ushort_t* Yob = Vtb + NXD;
    float* partial = (float*)(Yob + NXD);     // [8][16][1024]
    float* invcol = partial + 8 * 16 * 1024;  // [8][1024]

    conv_all<<<9728, 256, 0, stream>>>((const float4*)x, (const float4*)y,
                                       (const float4*)Wq, (const float4*)Wk,
                                       (const float4*)Wv, (short8*)xb, (short8*)yb,
                                       (short8*)wqb, (short8*)wkb, (short8*)wvb);

    // fused projections: Q=(x Wq^T)*0.125/ln2 (log2-domain), K=y Wk^T, Vt[b]=Wv y_b^T
    qkv_gemm<<<1536, 256, 0, stream>>>(xb, yb, wqb, wkb, wvb, Qb, Kbb, Vtb,
                                       0.125f * 1.44269504f);
    // fused per-head attention -> y_ [B*Nx, D] bf16
    flash_attn<<<1024, 256, 0, stream>>>(Qb, Kbb, Vtb, Yob);
    // out = exp2(x y_^T * 0.125/ln2) + per-column partial sums
    s_gemm<<<512, 256, 0, stream>>>(xb, Yob, out, 0.125f * 1.44269504f, partial);
    // inv column sums, then scale -> softmax over q (dim=-2)
    colsum_inv<<<32, 256, 0, stream>>>(partial, invcol);
    scale_rows<<<8192, 256, 0, stream>>>((float4*)out, (const float4*)invcol);
}